// Round 6
// baseline (92.373 us; speedup 1.0000x reference)
//
#include <hip/hip_runtime.h>
#include <hip/hip_bf16.h>

#define Hh 96
#define Ww 128
#define Cc 21
#define Nn (Hh * Ww)       // 12288
#define COLSZ (Hh * Cc)    // 2016 elements per image column
#define NF4 (COLSZ / 4)    // 504 quads per column
#define RAD 10             // dropped mass ~2e-4 rel; ~<=0.01 abs in q: ok
#define HALO (2 * RAD + 1) // 21 columns
#define TSTR 120           // tbuf per-channel stride (116 used, mult-of-4)
#define NT 512             // threads per block: 8 waves
#define FSTR 16            // flag stride in uints (64B line per column)

// bf16 helpers: p is stored packed bf16 (2 per uint) to halve Phase-A bytes.
__device__ __forceinline__ unsigned short f2bf(float f) {
  unsigned int u = __float_as_uint(f);
  u += 0x7fffu + ((u >> 16) & 1u);   // round-to-nearest-even
  return (unsigned short)(u >> 16);
}
__device__ __forceinline__ float bf2f_lo(unsigned int u) {
  return __uint_as_float(u << 16);
}
__device__ __forceinline__ float bf2f_hi(unsigned int u) {
  return __uint_as_float(u & 0xffff0000u);
}

// ---------------------------------------------------------------------------
// R13. vs R12 (kernel ~31us, e2e 89.6):
// 1) LOCAL p0 HALO: p0 = softmax(u) depends on nothing remote. Each block
//    computes p0 for all 21 clamped neighbor columns into LDS (rounded to
//    bf16 -> numerically identical to the values Phase A would have loaded
//    from global). Iteration 1's H-blur reads LDS; the entire first
//    {store -> flag -> poll -> load} IF round-trip link disappears (5 sync
//    links -> 4). Cost: ~2016 redundant 21-class softmaxes/block, fully
//    parallel, u mostly L2/L3-resident.
// 2) FUSED Phase C + softmax: per-row quad groups (4 lanes/row, lane g owns
//    cols 6g..), dot + u-subtract + in-register shfl_xor softmax + single
//    normalized write to qbuf. Removes one __syncthreads and one full qbuf
//    pass per iteration.
// Sync design unchanged from R12: per-column epoch flags, relaxed sc1
// accesses for all p traffic (IF-coherent, no fences), __syncthreads'
// vmcnt-drain doubles as release. 2-buffer safety: symmetric +-RAD
// read/write gating (see R12 argument). Spins bounded -> wrong answer on
// logic error, never a hang. Flags zeroed per launch via hipMemsetAsync.
// ---------------------------------------------------------------------------
__device__ __forceinline__ void wait_neighbors(const unsigned* __restrict__ flags,
                                               int x, unsigned needed) {
  if (threadIdx.x < HALO) {
    int xc = x - RAD + (int)threadIdx.x;
    xc = xc < 0 ? 0 : (xc >= Ww ? Ww - 1 : xc);
    const unsigned* f = flags + (size_t)xc * FSTR;
    for (int spin = 0; spin < (1 << 20); ++spin) {   // bounded watchdog
      if (__hip_atomic_load(f, __ATOMIC_RELAXED, __HIP_MEMORY_SCOPE_AGENT)
          >= needed) break;
      __builtin_amdgcn_s_sleep(1);
    }
  }
  __syncthreads();
}

__device__ __forceinline__ void post_flag(unsigned* __restrict__ flags,
                                          int x, unsigned e) {
  __syncthreads();   // every wave drained vmcnt(0): all sc1 p-stores visible
  if (threadIdx.x == 0)
    __hip_atomic_store(flags + (size_t)x * FSTR, e,
                       __ATOMIC_RELAXED, __HIP_MEMORY_SCOPE_AGENT);
}

// ---------------------------------------------------------------------------
__global__ __launch_bounds__(NT) void crf_fused_k(
    const float* __restrict__ u, const float* __restrict__ Ws,
    const float* __restrict__ Wb, const float* __restrict__ compat,
    unsigned long long* __restrict__ pa, unsigned long long* __restrict__ pb,
    unsigned int* __restrict__ flags, float* __restrict__ qout) {
  const int x = blockIdx.x, tid = threadIdx.x;

  __shared__ float w_ld[RAD + 1];
  __shared__ float ny_ld[Hh];
  __shared__ float M_ld[Cc * Cc];
  __shared__ float wsum_ld[Cc * Cc];
  __shared__ float cm_ld[Cc * Cc];
  __shared__ __align__(16) float tbuf[Cc * TSTR];        // [c][10|96|10+pad]
  __shared__ __align__(16) float sbuf[COLSZ];            // [h][c]
  __shared__ __align__(16) float qbuf[COLSZ];            // [h][c]
  __shared__ __align__(16) unsigned short phalo[HALO * COLSZ];  // p0, bf16

  // ---- per-row u registers for fused Phase C (lane g owns cols 6g..) ----
  const int r = tid >> 2, g = tid & 3;
  const int c0 = 6 * g;
  const int cN = (g < 3) ? 6 : 3;            // lane 3: cols 18..20
  float ureg[6];
  if (r < Hh) {
    #pragma unroll
    for (int q = 0; q < 6; ++q)
      if (q < cN) ureg[q] = u[((size_t)r * Ww + x) * Cc + c0 + q];
  }

  // ---- segment 1: tables + tbuf pad zeroing ----
  if (tid <= RAD) w_ld[tid] = __expf((float)(tid * tid) * (-1.f / 18.f));
  if (tid < Cc * Cc) { wsum_ld[tid] = Ws[tid] + Wb[tid]; cm_ld[tid] = compat[tid]; }
  {
    int i = tid;                       // Cc*2*RAD = 420 < NT: single pass
    if (i < Cc * 2 * RAD) {
      int c = i / (2 * RAD), gg = i % (2 * RAD);
      tbuf[c * TSTR + (gg < RAD ? gg : Hh + gg)] = 0.f;
    }
  }
  __syncthreads();

  // ---- segment 2: M = cm @ (Ws+Wb), ny, nx, and the LOCAL p0 HALO ----
  if (tid < Cc * Cc) {
    int a = tid / Cc, b = tid % Cc;
    float s = 0.f;
    #pragma unroll
    for (int kk = 0; kk < Cc; ++kk) s += cm_ld[a * Cc + kk] * wsum_ld[kk * Cc + b];
    M_ld[tid] = s;
  }
  if (tid < Hh) {
    float s = 0.f;
    #pragma unroll
    for (int d = -RAD; d <= RAD; ++d) {
      int hp = tid + d;
      if (hp >= 0 && hp < Hh) s += w_ld[d < 0 ? -d : d];
    }
    ny_ld[tid] = s;
  }
  float nxv = 0.f;
  #pragma unroll
  for (int d = -RAD; d <= RAD; ++d) {
    int xp = x + d;
    if (xp >= 0 && xp < Ww) nxv += w_ld[d < 0 ? -d : d];
  }

  // p0 halo: task t = (col j, row h); full 21-class softmax per task, packed
  // bf16 into phalo[j][h*Cc+c]. 2016 tasks over 512 threads x 4.
  #pragma unroll 2
  for (int k = 0; k < 4; ++k) {
    int t = tid + NT * k;
    if (t < HALO * Hh) {
      int j = t / Hh, h = t % Hh;
      int xc = x - RAD + j; xc = xc < 0 ? 0 : (xc >= Ww ? Ww - 1 : xc);
      const float* ub = u + ((size_t)h * Ww + xc) * Cc;
      float f[Cc];
      float m = -1e30f;
      #pragma unroll
      for (int c = 0; c < Cc; ++c) { f[c] = ub[c]; m = fmaxf(m, f[c]); }
      float s = 0.f;
      #pragma unroll
      for (int c = 0; c < Cc; ++c) { f[c] = __expf(f[c] - m); s += f[c]; }
      float inv = 1.f / s;
      unsigned short* dst = phalo + (size_t)j * COLSZ + h * Cc;
      #pragma unroll
      for (int c = 0; c < Cc; ++c) dst[c] = f2bf(f[c] * inv);
    }
  }
  __syncthreads();   // phalo + M_ld + ny_ld ready

  const unsigned long long* pin = pb;  // unused in iter 0
  unsigned long long* pout = pa;

  for (int it = 0; it < 5; ++it) {
    const int last = (it == 4);
    const bool af = (tid < NF4);
    float4 acc = {0.f, 0.f, 0.f, 0.f};

    // ---- Phase A: H-blur ----
    if (it == 0) {
      // taps from the local LDS halo (bf16-identical to the global path)
      if (af) {
        #pragma unroll
        for (int d = -RAD; d <= RAD; ++d) {
          int xs = x + d;
          float wv = (xs >= 0 && xs < Ww) ? w_ld[d < 0 ? -d : d] : 0.f;
          uint2 v = *(const uint2*)(phalo + (size_t)(d + RAD) * COLSZ + 4 * tid);
          acc.x += wv * bf2f_lo(v.x); acc.y += wv * bf2f_hi(v.x);
          acc.z += wv * bf2f_lo(v.y); acc.w += wv * bf2f_hi(v.y);
        }
      }
    } else {
      // neighbors must have posted epoch `it`
      wait_neighbors(flags, x, (unsigned)it);
      if (af) {
        unsigned long long pv[HALO];   // preload: one IF-latency batch
        #pragma unroll
        for (int d = -RAD; d <= RAD; ++d) {
          int xs = x + d;
          int xc = xs < 0 ? 0 : (xs >= Ww ? Ww - 1 : xs);
          pv[d + RAD] = __hip_atomic_load(pin + (size_t)xc * NF4 + tid,
                                          __ATOMIC_RELAXED,
                                          __HIP_MEMORY_SCOPE_AGENT);
        }
        #pragma unroll
        for (int d = -RAD; d <= RAD; ++d) {
          int xs = x + d;
          float wv = (xs >= 0 && xs < Ww) ? w_ld[d < 0 ? -d : d] : 0.f;
          unsigned lo = (unsigned)pv[d + RAD];
          unsigned hi = (unsigned)(pv[d + RAD] >> 32);
          acc.x += wv * bf2f_lo(lo); acc.y += wv * bf2f_hi(lo);
          acc.z += wv * bf2f_lo(hi); acc.w += wv * bf2f_hi(hi);
        }
      }
    }
    if (af) {   // scatter into transposed padded tbuf [c][RAD+h]
      float a4[4] = {acc.x, acc.y, acc.z, acc.w};
      #pragma unroll
      for (int e = 0; e < 4; ++e) {
        int i = 4 * tid + e;
        tbuf[(i % Cc) * TSTR + RAD + (i / Cc)] = a4[e];
      }
    }
    __syncthreads();

    // ---- Phase B: V-blur (aligned float4 LDS reads) + normalize ----
    if (tid < NF4) {               // 504 = 21 c * 24 h-quads
      int c = tid / 24, q = tid % 24;
      int h0 = 4 * q;
      const float* base = tbuf + c * TSTR + h0;  // padded idx of h0-RAD
      float rr[4] = {0.f, 0.f, 0.f, 0.f};
      #pragma unroll
      for (int jj = 0; jj < 6; ++jj) {      // offsets 0..23 cover d in [-10,13]
        float4 tv = *(const float4*)(base + 4 * jj);
        float tvv[4] = {tv.x, tv.y, tv.z, tv.w};
        #pragma unroll
        for (int kk = 0; kk < 4; ++kk) {
          #pragma unroll
          for (int o = 0; o < 4; ++o) {
            int d = 4 * jj + kk - RAD - o;  // compile-time after unroll
            int ad = d < 0 ? -d : d;
            if (ad <= RAD) rr[o] += w_ld[ad] * tvv[kk];
          }
        }
      }
      #pragma unroll
      for (int o = 0; o < 4; ++o)
        sbuf[(h0 + o) * Cc + c] = rr[o] / (nxv * ny_ld[h0 + o]);
    }
    __syncthreads();

    // ---- Phase C (fused): per-row dot + u-subtract + in-register softmax.
    // Quad lanes (r,g): lane g owns cols c0..c0+cN-1; shfl_xor(1|2) stays
    // inside the quad (rows are 4-lane-aligned).
    if (r < Hh) {
      float qv[6];
      #pragma unroll
      for (int q = 0; q < 6; ++q) {
        if (q < cN) {
          int cc = c0 + q;
          float a = 0.f;
          #pragma unroll
          for (int b = 0; b < Cc; ++b) a += M_ld[cc * Cc + b] * sbuf[r * Cc + b];
          qv[q] = ureg[q] - a;
        }
      }
      if (last) {
        #pragma unroll
        for (int q = 0; q < 6; ++q)
          if (q < cN) qbuf[r * Cc + c0 + q] = qv[q];
      } else {
        float m = -1e30f;
        #pragma unroll
        for (int q = 0; q < 6; ++q) if (q < cN) m = fmaxf(m, qv[q]);
        m = fmaxf(m, __shfl_xor(m, 1));
        m = fmaxf(m, __shfl_xor(m, 2));
        float s = 0.f;
        #pragma unroll
        for (int q = 0; q < 6; ++q)
          if (q < cN) { qv[q] = __expf(qv[q] - m); s += qv[q]; }
        s += __shfl_xor(s, 1);
        s += __shfl_xor(s, 2);
        float inv = 1.f / s;
        #pragma unroll
        for (int q = 0; q < 6; ++q)
          if (q < cN) qbuf[r * Cc + c0 + q] = qv[q] * inv;
      }
    }
    __syncthreads();

    if (last) {                    // block-uniform branch
      if (tid < NF4)
        *(float4*)(qout + (size_t)x * COLSZ + 4 * tid) = *(const float4*)(qbuf + 4 * tid);
    } else {
      if (tid < NF4) {   // pack 4 fp32 -> 4 bf16 in one 8B coherent store
        float4 v = *(const float4*)(qbuf + 4 * tid);
        unsigned lo = (unsigned)f2bf(v.x) | ((unsigned)f2bf(v.y) << 16);
        unsigned hi = (unsigned)f2bf(v.z) | ((unsigned)f2bf(v.w) << 16);
        unsigned long long o = (unsigned long long)lo | ((unsigned long long)hi << 32);
        __hip_atomic_store(pout + (size_t)x * NF4 + tid, o,
                           __ATOMIC_RELAXED, __HIP_MEMORY_SCOPE_AGENT);
      }
      post_flag(flags, x, (unsigned)(it + 1));   // epoch it+1 ready
      const unsigned long long* t = pin; pin = pout;
      pout = (unsigned long long*)t;
    }
  }
}

// ---------------------------------------------------------------------------
extern "C" void kernel_launch(void* const* d_in, const int* in_sizes, int n_in,
                              void* d_out, int out_size, void* d_ws, size_t ws_size,
                              hipStream_t stream) {
  const float* u      = (const float*)d_in[0];  // (1,H,W,C)
  // d_in[1] = rgb: DEAD (replicated source bug uses spatial_out twice)
  const float* Ws     = (const float*)d_in[2];
  const float* Wb     = (const float*)d_in[3];
  const float* compat = (const float*)d_in[4];
  float* out = (float*)d_out;

  unsigned long long* pa = (unsigned long long*)d_ws;  // bf16x4 per 8B
  unsigned long long* pb = pa + (size_t)Ww * NF4;
  unsigned int* flags = (unsigned int*)(pb + (size_t)Ww * NF4);

  // Zero flag state EVERY launch (graph-capturable stream op; workspace is
  // poisoned between harness iterations, so flags MUST be re-zeroed).
  hipMemsetAsync(flags, 0, Ww * FSTR * sizeof(unsigned), stream);

  crf_fused_k<<<dim3(Ww), dim3(NT), 0, stream>>>(u, Ws, Wb, compat,
                                                 pa, pb, flags, out);
}

// Round 7
// 90.713 us; speedup vs baseline: 1.0183x; 1.0183x over previous
//
#include <hip/hip_runtime.h>
#include <hip/hip_bf16.h>

#define Hh 96
#define Ww 128
#define Cc 21
#define Nn (Hh * Ww)       // 12288
#define COLSZ (Hh * Cc)    // 2016 elements per image column
#define NF4 (COLSZ / 4)    // 504 quads per column
#define RAD 10             // dropped mass ~2e-4 rel; ~<=0.01 abs in q: ok
#define HALO (2 * RAD + 1) // 21 columns
#define TSTR 120           // tbuf per-channel stride (116 used, mult-of-4)
#define NT 512             // threads per block: 8 waves
#define FSTR 16            // flag stride in uints (64B line per column)

// bf16 helpers: p is stored packed bf16 (2 per uint) to halve Phase-A bytes.
__device__ __forceinline__ unsigned short f2bf(float f) {
  unsigned int u = __float_as_uint(f);
  u += 0x7fffu + ((u >> 16) & 1u);   // round-to-nearest-even
  return (unsigned short)(u >> 16);
}
__device__ __forceinline__ float bf2f_lo(unsigned int u) {
  return __uint_as_float(u << 16);
}
__device__ __forceinline__ float bf2f_hi(unsigned int u) {
  return __uint_as_float(u & 0xffff0000u);
}

// ---------------------------------------------------------------------------
// R14. R13 post-mortem: p0-halo REGRESSED (-3us): it added ~2us of serial
// setup (83 expf/thread + scattered u re-reads) on the critical path before
// iter 1 to save one ~2us sync link, and ballooned LDS to 114KB. Reverted.
// Kept from R13: fused Phase C (dot + u-subtract + in-register quad softmax,
// one barrier and one qbuf pass fewer per iteration).
// New in R14 -- hide the first link instead of eliminating it:
//   * p0 computed ENTIRELY in registers from ureg (same quad-shfl reduction
//     order as R12's softmax_rows -> bit-identical), single normalized qbuf
//     write, pack -> sc1 store -> post flag 1 as the FIRST thing the block
//     does after the u gather.
//   * ALL setup (w table, ny, nxv, M, tbuf pad zeroing) moved AFTER the
//     flag post: it executes while flag 1 and neighbors' p0 stores
//     propagate through IF -- the first link's latency is hidden behind
//     real work (R12 serialized setup BEFORE p0, exposing the link).
//   * M computed directly from global (compat/Ws/Wb = 1.7KB each, L1-hot):
//     deletes wsum/cm LDS staging and one setup barrier.
// Sync design unchanged from R12: per-column epoch flags (one writer each),
// relaxed sc1 for all p traffic (IF-coherent, fence-free), __syncthreads'
// vmcnt-drain doubles as release. 2-buffer safety: symmetric +-RAD
// read/write gating (R12 argument). Spins bounded (hot-spin 256 rounds,
// then s_sleep(1)) -> logic error = wrong answer, never a hung container.
// Flags zeroed every launch via hipMemsetAsync (workspace is poisoned
// between harness iterations).
// ---------------------------------------------------------------------------
__device__ __forceinline__ void wait_neighbors(const unsigned* __restrict__ flags,
                                               int x, unsigned needed) {
  if (threadIdx.x < HALO) {
    int xc = x - RAD + (int)threadIdx.x;
    xc = xc < 0 ? 0 : (xc >= Ww ? Ww - 1 : xc);
    const unsigned* f = flags + (size_t)xc * FSTR;
    for (int spin = 0; spin < (1 << 20); ++spin) {   // bounded watchdog
      if (__hip_atomic_load(f, __ATOMIC_RELAXED, __HIP_MEMORY_SCOPE_AGENT)
          >= needed) break;
      if (spin > 256) __builtin_amdgcn_s_sleep(1);
    }
  }
  __syncthreads();
}

__device__ __forceinline__ void post_flag(unsigned* __restrict__ flags,
                                          int x, unsigned e) {
  __syncthreads();   // every wave drained vmcnt(0): all sc1 p-stores visible
  if (threadIdx.x == 0)
    __hip_atomic_store(flags + (size_t)x * FSTR, e,
                       __ATOMIC_RELAXED, __HIP_MEMORY_SCOPE_AGENT);
}

// ---------------------------------------------------------------------------
__global__ __launch_bounds__(NT) void crf_fused_k(
    const float* __restrict__ u, const float* __restrict__ Ws,
    const float* __restrict__ Wb, const float* __restrict__ compat,
    unsigned long long* __restrict__ pa, unsigned long long* __restrict__ pb,
    unsigned int* __restrict__ flags, float* __restrict__ qout) {
  const int x = blockIdx.x, tid = threadIdx.x;

  __shared__ float w_ld[RAD + 1];
  __shared__ float ny_ld[Hh];
  __shared__ float M_ld[Cc * Cc];
  __shared__ __align__(16) float tbuf[Cc * TSTR];  // [c][10|96|10+pad]
  __shared__ __align__(16) float sbuf[COLSZ];      // [h][c]
  __shared__ __align__(16) float qbuf[COLSZ];      // [h][c]

  // ---- per-row u registers (lane g of row r owns cols 6g..6g+cN-1) ----
  const int r = tid >> 2, g = tid & 3;
  const int c0 = 6 * g;
  const int cN = (g < 3) ? 6 : 3;            // lane 3: cols 18..20
  float ureg[6];
  if (r < Hh) {
    #pragma unroll
    for (int q = 0; q < 6; ++q)
      if (q < cN) ureg[q] = u[((size_t)r * Ww + x) * Cc + c0 + q];
  }

  // ---- p0 = softmax(u) fully in registers; single normalized qbuf write ----
  if (r < Hh) {
    float pv[6];
    float m = -1e30f;
    #pragma unroll
    for (int q = 0; q < 6; ++q)
      if (q < cN) { pv[q] = ureg[q]; m = fmaxf(m, pv[q]); }
    m = fmaxf(m, __shfl_xor(m, 1));
    m = fmaxf(m, __shfl_xor(m, 2));
    float s = 0.f;
    #pragma unroll
    for (int q = 0; q < 6; ++q)
      if (q < cN) { pv[q] = __expf(pv[q] - m); s += pv[q]; }
    s += __shfl_xor(s, 1);
    s += __shfl_xor(s, 2);
    float inv = 1.f / s;
    #pragma unroll
    for (int q = 0; q < 6; ++q)
      if (q < cN) qbuf[r * Cc + c0 + q] = pv[q] * inv;
  }
  __syncthreads();
  if (tid < NF4) {   // pack 4 fp32 -> 4 bf16 in one 8B coherent store
    float4 v = *(const float4*)(qbuf + 4 * tid);
    unsigned lo = (unsigned)f2bf(v.x) | ((unsigned)f2bf(v.y) << 16);
    unsigned hi = (unsigned)f2bf(v.z) | ((unsigned)f2bf(v.w) << 16);
    unsigned long long o = (unsigned long long)lo | ((unsigned long long)hi << 32);
    __hip_atomic_store(pa + (size_t)x * NF4 + tid, o,
                       __ATOMIC_RELAXED, __HIP_MEMORY_SCOPE_AGENT);
  }
  // w_ld written here rides post_flag's barrier (read only after it).
  if (tid <= RAD) w_ld[tid] = __expf((float)(tid * tid) * (-1.f / 18.f));
  post_flag(flags, x, 1u);   // epoch 1: p0 published

  // ---- setup, overlapped with flag/p0 IF propagation ----
  // (all LDS writes below are covered by wait_neighbors' barrier in iter 0)
  if (tid < Cc * Cc) {       // M = compat @ (Ws+Wb), direct from global (L1-hot)
    int a = tid / Cc, b = tid % Cc;
    float s = 0.f;
    #pragma unroll
    for (int kk = 0; kk < Cc; ++kk)
      s += compat[a * Cc + kk] * (Ws[kk * Cc + b] + Wb[kk * Cc + b]);
    M_ld[tid] = s;
  }
  if (tid < Hh) {            // ny: truncated consistently with the blur
    float s = 0.f;
    #pragma unroll
    for (int d = -RAD; d <= RAD; ++d) {
      int hp = tid + d;
      if (hp >= 0 && hp < Hh) s += w_ld[d < 0 ? -d : d];
    }
    ny_ld[tid] = s;
  }
  {                          // zero vertical pads of tbuf (write-once)
    int i = tid;             // Cc*2*RAD = 420 < NT: single pass
    if (i < Cc * 2 * RAD) {
      int c = i / (2 * RAD), gg = i % (2 * RAD);
      tbuf[c * TSTR + (gg < RAD ? gg : Hh + gg)] = 0.f;
    }
  }
  float nxv = 0.f;
  #pragma unroll
  for (int d = -RAD; d <= RAD; ++d) {
    int xp = x + d;
    if (xp >= 0 && xp < Ww) nxv += w_ld[d < 0 ? -d : d];
  }

  const unsigned long long* pin = pa;
  unsigned long long* pout = pb;

  for (int it = 0; it < 5; ++it) {
    const int last = (it == 4);
    const bool af = (tid < NF4);

    // ---- wait for the 21 clamped neighbor columns to reach this epoch ----
    wait_neighbors(flags, x, (unsigned)(it + 1));

    // ---- Phase A: H-blur. Preload all 21 sc1 taps (one IF-latency batch),
    // then unpack+FMA; static indexing after unroll -> registers.
    float4 acc = {0.f, 0.f, 0.f, 0.f};
    if (af) {
      unsigned long long pv[HALO];
      #pragma unroll
      for (int d = -RAD; d <= RAD; ++d) {
        int xs = x + d;
        int xc = xs < 0 ? 0 : (xs >= Ww ? Ww - 1 : xs);
        pv[d + RAD] = __hip_atomic_load(pin + (size_t)xc * NF4 + tid,
                                        __ATOMIC_RELAXED,
                                        __HIP_MEMORY_SCOPE_AGENT);
      }
      #pragma unroll
      for (int d = -RAD; d <= RAD; ++d) {
        int xs = x + d;
        float wv = (xs >= 0 && xs < Ww) ? w_ld[d < 0 ? -d : d] : 0.f;
        unsigned lo = (unsigned)pv[d + RAD];
        unsigned hi = (unsigned)(pv[d + RAD] >> 32);
        acc.x += wv * bf2f_lo(lo); acc.y += wv * bf2f_hi(lo);
        acc.z += wv * bf2f_lo(hi); acc.w += wv * bf2f_hi(hi);
      }
      float a4[4] = {acc.x, acc.y, acc.z, acc.w};   // scatter [c][RAD+h]
      #pragma unroll
      for (int e = 0; e < 4; ++e) {
        int i = 4 * tid + e;
        tbuf[(i % Cc) * TSTR + RAD + (i / Cc)] = a4[e];
      }
    }
    __syncthreads();

    // ---- Phase B: V-blur (aligned float4 LDS reads) + normalize ----
    if (tid < NF4) {               // 504 = 21 c * 24 h-quads
      int c = tid / 24, q = tid % 24;
      int h0 = 4 * q;
      const float* base = tbuf + c * TSTR + h0;  // padded idx of h0-RAD
      float rr[4] = {0.f, 0.f, 0.f, 0.f};
      #pragma unroll
      for (int jj = 0; jj < 6; ++jj) {      // offsets 0..23 cover d in [-10,13]
        float4 tv = *(const float4*)(base + 4 * jj);
        float tvv[4] = {tv.x, tv.y, tv.z, tv.w};
        #pragma unroll
        for (int kk = 0; kk < 4; ++kk) {
          #pragma unroll
          for (int o = 0; o < 4; ++o) {
            int d = 4 * jj + kk - RAD - o;  // compile-time after unroll
            int ad = d < 0 ? -d : d;
            if (ad <= RAD) rr[o] += w_ld[ad] * tvv[kk];
          }
        }
      }
      #pragma unroll
      for (int o = 0; o < 4; ++o)
        sbuf[(h0 + o) * Cc + c] = rr[o] / (nxv * ny_ld[h0 + o]);
    }
    __syncthreads();

    // ---- Phase C (fused): per-row dot + u-subtract + in-register quad
    // softmax; single qbuf write (normalized p, or raw q if last).
    if (r < Hh) {
      float qv[6];
      #pragma unroll
      for (int q = 0; q < 6; ++q) {
        if (q < cN) {
          int cc = c0 + q;
          float a = 0.f;
          #pragma unroll
          for (int b = 0; b < Cc; ++b) a += M_ld[cc * Cc + b] * sbuf[r * Cc + b];
          qv[q] = ureg[q] - a;
        }
      }
      if (last) {
        #pragma unroll
        for (int q = 0; q < 6; ++q)
          if (q < cN) qbuf[r * Cc + c0 + q] = qv[q];
      } else {
        float m = -1e30f;
        #pragma unroll
        for (int q = 0; q < 6; ++q) if (q < cN) m = fmaxf(m, qv[q]);
        m = fmaxf(m, __shfl_xor(m, 1));
        m = fmaxf(m, __shfl_xor(m, 2));
        float s = 0.f;
        #pragma unroll
        for (int q = 0; q < 6; ++q)
          if (q < cN) { qv[q] = __expf(qv[q] - m); s += qv[q]; }
        s += __shfl_xor(s, 1);
        s += __shfl_xor(s, 2);
        float inv = 1.f / s;
        #pragma unroll
        for (int q = 0; q < 6; ++q)
          if (q < cN) qbuf[r * Cc + c0 + q] = qv[q] * inv;
      }
    }
    __syncthreads();

    if (last) {                    // block-uniform branch
      if (tid < NF4)
        *(float4*)(qout + (size_t)x * COLSZ + 4 * tid) = *(const float4*)(qbuf + 4 * tid);
    } else {
      if (tid < NF4) {   // pack 4 fp32 -> 4 bf16 in one 8B coherent store
        float4 v = *(const float4*)(qbuf + 4 * tid);
        unsigned lo = (unsigned)f2bf(v.x) | ((unsigned)f2bf(v.y) << 16);
        unsigned hi = (unsigned)f2bf(v.z) | ((unsigned)f2bf(v.w) << 16);
        unsigned long long o = (unsigned long long)lo | ((unsigned long long)hi << 32);
        __hip_atomic_store(pout + (size_t)x * NF4 + tid, o,
                           __ATOMIC_RELAXED, __HIP_MEMORY_SCOPE_AGENT);
      }
      post_flag(flags, x, (unsigned)(it + 2));   // epoch it+2 ready
      const unsigned long long* t = pin; pin = pout;
      pout = (unsigned long long*)t;
    }
  }
}

// ---------------------------------------------------------------------------
extern "C" void kernel_launch(void* const* d_in, const int* in_sizes, int n_in,
                              void* d_out, int out_size, void* d_ws, size_t ws_size,
                              hipStream_t stream) {
  const float* u      = (const float*)d_in[0];  // (1,H,W,C)
  // d_in[1] = rgb: DEAD (replicated source bug uses spatial_out twice)
  const float* Ws     = (const float*)d_in[2];
  const float* Wb     = (const float*)d_in[3];
  const float* compat = (const float*)d_in[4];
  float* out = (float*)d_out;

  unsigned long long* pa = (unsigned long long*)d_ws;  // bf16x4 per 8B
  unsigned long long* pb = pa + (size_t)Ww * NF4;
  unsigned int* flags = (unsigned int*)(pb + (size_t)Ww * NF4);

  // Zero flag state EVERY launch (graph-capturable stream op; workspace is
  // poisoned between harness iterations, so flags MUST be re-zeroed).
  hipMemsetAsync(flags, 0, Ww * FSTR * sizeof(unsigned), stream);

  crf_fused_k<<<dim3(Ww), dim3(NT), 0, stream>>>(u, Ws, Wb, compat,
                                                 pa, pb, flags, out);
}